// Round 1
// baseline (121.105 us; speedup 1.0000x reference)
//
#include <hip/hip_runtime.h>

#define BSZ 8
#define PN  2048
#define CIN 512
#define CAP 2048
#define NW  16

// ws layout (bytes):
//   accum @ 0       : 8 floats (S[4], imb[4]) + int counter @ accum[8]
//   meta  @ 64      : 24 ints (padded list length per (b,c))
//   sList @ 1024    : 24*2048 floats   (score, list order)
//   areaL @ 197632  : 24*2048 floats   (precomputed area)
//   roiL  @ 394240  : 24*2048 float4   (roi, list order)
//   pbn   @ 1180672 : 24*2*2048 floats (partial best numerator)
//   pbd   @ 1573888 : 24*2*2048 floats (partial best denominator)
//   pbp   @ 1967104 : 24*2*2048 ints   (partial best list position)

// ---------------- K1: selection -> compacted per-(b,c) lists ----------------
__global__ __launch_bounds__(256) void k_sel(
    const float* __restrict__ ps, const float* __restrict__ labels,
    const float* __restrict__ rois, float* __restrict__ accum,
    int* __restrict__ meta, float* __restrict__ sList,
    float* __restrict__ areaL, float4* __restrict__ roiList)
{
  const int t  = threadIdx.x;
  const int bc = blockIdx.x;                        // 0..23
  if (bc == 0 && t < 12) accum[t] = 0.0f;           // zero sums + ticket counter
  const int b = bc / 3;
  const int c = bc % 3;
  const int j0 = t * 8;

  float sv[8];
  int   flg = 0, cnt = 0;
  float vmax = -1e30f;
  int   jmax = 0;
  #pragma unroll
  for (int m = 0; m < 8; ++m) {
    const float s = ps[(b * PN + j0 + m) * 4 + c];
    sv[m] = s;
    if (s > 0.5f) { flg |= 1 << m; ++cnt; }
    if (s > vmax) { vmax = s; jmax = j0 + m; }      // ascending: > = first
  }

  __shared__ float lv[256];
  __shared__ int   lj[256];
  __shared__ int   pre[256];
  lv[t] = vmax; lj[t] = jmax; pre[t] = cnt;
  __syncthreads();
  for (int off = 128; off > 0; off >>= 1) {         // argmax reduce
    if (t < off) {
      const float v2 = lv[t + off]; const int j2 = lj[t + off];
      if (v2 > lv[t] || (v2 == lv[t] && j2 < lj[t])) { lv[t] = v2; lj[t] = j2; }
    }
    __syncthreads();
  }
  for (int off = 1; off < 256; off <<= 1) {         // inclusive scan
    const int add = (t >= off) ? pre[t - off] : 0;
    __syncthreads();
    pre[t] += add;
    __syncthreads();
  }
  const int  totalTh = pre[255];
  const int  excl    = pre[t] - cnt;
  const int  jArg    = lj[0];
  const bool lab     = labels[b * 4 + c] != 0.0f;
  const int  L    = (!lab) ? 0 : ((totalTh > 1) ? totalTh : 1);
  const int  Lpad = (L + 7) & ~7;

  __shared__ float4 lastRoi;
  __shared__ float  lastS, lastA;
  float4* dstR = roiList + bc * CAP;
  float*  dstS = sList   + bc * CAP;
  float*  dstA = areaL   + bc * CAP;
  const float4* rb = ((const float4*)rois) + b * PN;

  if (lab) {
    if (totalTh > 1) {
      int pos = excl;
      #pragma unroll
      for (int m = 0; m < 8; ++m) {
        if (flg & (1 << m)) {
          const float4 r = rb[j0 + m];
          const float  a = (r.z - r.x) * (r.w - r.y);
          dstR[pos] = r; dstS[pos] = sv[m]; dstA[pos] = a;
          if (pos == L - 1) { lastRoi = r; lastS = sv[m]; lastA = a; }
          ++pos;
        }
      }
    } else if (t == (jArg >> 3)) {
      const float4 r = rb[jArg];
      const float  a = (r.z - r.x) * (r.w - r.y);
      dstR[0] = r; dstS[0] = sv[jArg & 7]; dstA[0] = a;
      lastRoi = r; lastS = sv[jArg & 7]; lastA = a;
    }
  }
  __syncthreads();
  if (t < Lpad - L) { dstR[L + t] = lastRoi; dstS[L + t] = lastS; dstA[L + t] = lastA; }
  if (t == 0) meta[bc] = Lpad;
}

// ---------------- K2: IoU partials + fc/softmax interleaved ------------------
// block = (b, itile64, half h). j-lists are read via wave-uniform (scalar-path)
// loads -- no LDS staging. fc rows (2/wave) hide their HBM stream under the
// IoU VALU phases: x prefetch issued one phase ahead of consumption; the only
// barrier between issue and use is the sW barrier placed right before the
// first fc compute (by which time the loads have long returned).
__global__ __launch_bounds__(1024, 8) void k_mid(
    const float* __restrict__ inp, const float* __restrict__ fcw,
    const float* __restrict__ fcb, const float* __restrict__ rois,
    const int* __restrict__ meta, const float4* __restrict__ roiList,
    const float* __restrict__ areaL, float* __restrict__ logit,
    float* __restrict__ pbn, float* __restrict__ pbd, int* __restrict__ pbp)
{
  const int blk   = blockIdx.x;
  const int h     = blk & 1;
  const int itile = (blk >> 1) & 31;
  const int b     = blk >> 6;
  const int t     = threadIdx.x;
  const int lane  = t & 63;
  const int wv    = t >> 6;

  __shared__ float sW[2048];                        // transposed W: [o][k], 8 KB
  __shared__ float mn[3 * NW * 64];                 // 12 KB
  __shared__ float md[3 * NW * 64];                 // 12 KB
  __shared__ int   mp[3 * NW * 64];                 // 12 KB

  // fc x prefetch (row 0 of this wave's pair) -- issued first, covered by c=0
  const int gw2 = (blk << 4) + wv;                  // 0..8191
  const int r0  = gw2 << 1;                         // rows r0, r0+1
  const int kb  = lane << 2;
  const float* xrow0 = inp + r0 * CIN;
  const float4 x0a = *(const float4*)(xrow0 + kb);
  const float4 x0b = *(const float4*)(xrow0 + 256 + kb);
  const float4 bias = *(const float4*)fcb;          // uniform -> SGPR

  // stage transposed weights: sW[o*512+k] = fcw[k*4+o]
  {
    int idx = t;
    sW[idx] = fcw[(idx & 511) * 4 + (idx >> 9)];
    idx = t + 1024;
    sW[idx] = fcw[(idx & 511) * 4 + (idx >> 9)];
  }

  const int i = (itile << 6) + lane;
  const float4 ri = ((const float4*)rois)[b * PN + i];
  const float areai = (ri.z - ri.x) * (ri.w - ri.y);

  int startc[3], cntc[3];
  #pragma unroll
  for (int c = 0; c < 3; ++c) {
    const int L  = meta[b * 3 + c];                 // padded, mult of 8
    const int L2 = ((L >> 1) + 7) & ~7;             // h-split point
    startc[c] = h ? L2 : 0;
    cntc[c]   = (h ? L : L2) - startc[c];           // <= 1024, mult of 8
  }

  float BN[3], BD[3]; int BP[3];

  auto upd = [&](float& n, float& d, int& p,
                 const float4 rj, const float aj, const int pos) {
    const float lx = fmaxf(ri.x, rj.x), ly = fmaxf(ri.y, rj.y);
    const float rx = fminf(ri.z, rj.z), ry = fminf(ri.w, rj.w);
    const float ww = fmaxf(rx - lx, 0.0f), hh = fmaxf(ry - ly, 0.0f);
    const float inter = ww * hh;
    const float uni   = areai + aj - inter;         // >= 1 always
    if (inter * d > n * uni) { n = inter; d = uni; p = pos; }
  };

  auto iou_c = [&](const int c) {
    const int cnt = cntc[c];
    const int C   = (((cnt + 15) >> 4) + 7) & ~7;   // per-wave chunk, mult 8
    int g0 = wv * C;
    int g1 = g0 + C; if (g1 > cnt) g1 = cnt;
    g0 = __builtin_amdgcn_readfirstlane(g0);        // force wave-uniform loop
    g1 = __builtin_amdgcn_readfirstlane(g1);
    const float4* __restrict__ rbase = roiList + (b * 3 + c) * CAP + startc[c];
    const float*  __restrict__ abase = areaL   + (b * 3 + c) * CAP + startc[c];
    float nA = -2.0f, dA = 1.0f, nB = -2.0f, dB = 1.0f;
    int   pA = 0, pB = 0;
    for (int g = g0; g < g1; g += 4) {              // uniform addr -> s_load path
      const float4 r0_ = rbase[g],   r1_ = rbase[g+1];
      const float4 r2_ = rbase[g+2], r3_ = rbase[g+3];
      const float  a0_ = abase[g],   a1_ = abase[g+1];
      const float  a2_ = abase[g+2], a3_ = abase[g+3];
      upd(nA, dA, pA, r0_, a0_, g);                 // chain A: g, g+1
      upd(nB, dB, pB, r2_, a2_, g + 2);             // chain B: g+2, g+3
      upd(nA, dA, pA, r1_, a1_, g + 1);
      upd(nB, dB, pB, r3_, a3_, g + 3);
    }
    // merge B into A; exact tie -> lower position (ref = first max)
    const float tB = nB * dA, tA = nA * dB;
    if (tB > tA || (tB == tA && pB < pA)) { nA = nB; dA = dB; pA = pB; }
    BN[c] = nA; BD[c] = dA; BP[c] = pA + startc[c];
  };

  auto fc_row = [&](const int r, const float4 xa, const float4 xb) {
    const float4* w4 = (const float4*)sW;
    float a0, a1, a2, a3;
    {                                               // half 1: 16 w-regs peak
      const float4 w0 = w4[      lane], w1 = w4[128 + lane];
      const float4 w2 = w4[256 + lane], w3 = w4[384 + lane];
      a0 = xa.x*w0.x + xa.y*w0.y + xa.z*w0.z + xa.w*w0.w;
      a1 = xa.x*w1.x + xa.y*w1.y + xa.z*w1.z + xa.w*w1.w;
      a2 = xa.x*w2.x + xa.y*w2.y + xa.z*w2.z + xa.w*w2.w;
      a3 = xa.x*w3.x + xa.y*w3.y + xa.z*w3.z + xa.w*w3.w;
    }
    {                                               // half 2
      const float4 w0 = w4[ 64 + lane], w1 = w4[192 + lane];
      const float4 w2 = w4[320 + lane], w3 = w4[448 + lane];
      a0 += xb.x*w0.x + xb.y*w0.y + xb.z*w0.z + xb.w*w0.w;
      a1 += xb.x*w1.x + xb.y*w1.y + xb.z*w1.z + xb.w*w1.w;
      a2 += xb.x*w2.x + xb.y*w2.y + xb.z*w2.z + xb.w*w2.w;
      a3 += xb.x*w3.x + xb.y*w3.y + xb.z*w3.z + xb.w*w3.w;
    }
    #pragma unroll
    for (int off = 32; off; off >>= 1) {
      a0 += __shfl_xor(a0, off); a1 += __shfl_xor(a1, off);
      a2 += __shfl_xor(a2, off); a3 += __shfl_xor(a3, off);
    }
    if (lane == 0) {
      a0 += bias.x; a1 += bias.y; a2 += bias.z; a3 += bias.w;
      const float m  = fmaxf(fmaxf(a0, a1), fmaxf(a2, a3));
      const float e0 = expf(a0 - m), e1 = expf(a1 - m);
      const float e2 = expf(a2 - m), e3 = expf(a3 - m);
      const float inv = 1.0f / (e0 + e1 + e2 + e3);
      float4 o; o.x = e0*inv; o.y = e1*inv; o.z = e2*inv; o.w = e3*inv;
      *(float4*)(logit + r * 4) = o;
    }
  };

  iou_c(0);                                         // x0 stream hides here

  __syncthreads();                                  // sW ready (drains x0 too,
                                                    // which fc_row needs anyway)
  fc_row(r0, x0a, x0b);

  const float* xrow1 = xrow0 + CIN;                 // prefetch row 1
  const float4 x1a = *(const float4*)(xrow1 + kb);
  const float4 x1b = *(const float4*)(xrow1 + 256 + kb);

  iou_c(1);                                         // x1 stream hides here
  fc_row(r0 + 1, x1a, x1b);
  iou_c(2);

  #pragma unroll
  for (int c = 0; c < 3; ++c) {
    mn[(c * NW + wv) * 64 + lane] = BN[c];
    md[(c * NW + wv) * 64 + lane] = BD[c];
    mp[(c * NW + wv) * 64 + lane] = BP[c];
  }
  __syncthreads();
  if (wv == 0) {
    #pragma unroll
    for (int c = 0; c < 3; ++c) {
      float bn = BN[c], bd = BD[c]; int bp = BP[c];
      for (int w2 = 1; w2 < NW; ++w2) {             // wv-ascending: > = first
        const float n = mn[(c * NW + w2) * 64 + lane];
        const float d = md[(c * NW + w2) * 64 + lane];
        const int   p = mp[(c * NW + w2) * 64 + lane];
        if (n * bd > bn * d) { bn = n; bd = d; bp = p; }
      }
      const int o = ((b * 3 + c) * 2 + h) * PN + i;
      pbn[o] = bn; pbd[o] = bd; pbp[o] = bp;
    }
  }
}

// ---------------- K3: merge halves + epilogue + loss (ticketed finalize) -----
__global__ __launch_bounds__(256) void k_back(
    const float* __restrict__ pbn, const float* __restrict__ pbd,
    const int* __restrict__ pbp, const float* __restrict__ sList,
    const float* __restrict__ logit, const float* __restrict__ labels,
    float* __restrict__ accum, float* __restrict__ loss)
{
  const int t  = threadIdx.x;
  const int gi = blockIdx.x * 256 + t;              // 0..16383
  const int b  = gi >> 11;
  const int i  = gi & (PN - 1);

  float v[3], sc[3];
  #pragma unroll
  for (int c = 0; c < 3; ++c) {
    const int o0 = ((b * 3 + c) * 2) * PN + i;
    float n = pbn[o0], d = pbd[o0]; int p = pbp[o0];
    const float n1 = pbn[o0 + PN], d1 = pbd[o0 + PN];
    const int   p1 = pbp[o0 + PN];
    if (n1 * d > n * d1) { n = n1; d = d1; p = p1; }  // h-ascending: > = first
    v[c]  = n / d;                                    // exact IEEE divide
    sc[c] = sList[(b * 3 + c) * CAP + p];
  }
  float runI = -1.0f, runw = 1.0f;
  if (v[0] > runI) { runw = sc[0]; runI = v[0]; }
  if (v[1] > runI) { runw = sc[1]; runI = v[1]; }
  if (v[2] > runI) { runw = sc[2]; runI = v[2]; }
  const float y0 = (v[0] > 0.5f) ? 1.0f : 0.0f;
  const float y1 = (v[1] > 0.5f) ? 1.0f : 0.0f;
  const float y2 = (v[2] > 0.5f) ? 1.0f : 0.0f;
  const float y3 = (y0 + y1 + y2 == 0.0f) ? 1.0f : 0.0f;

  const float4 lg = ((const float4*)logit)[gi];
  const float lb0 = labels[b * 4 + 0];
  const float lb1 = labels[b * 4 + 1];
  const float lb2 = labels[b * 4 + 2];

  auto term = [&](const float l, const float yv, const float labv) -> float {
    const float p  = fminf(fmaxf(l, 1e-7f), 1.0f - 1e-7f);
    const float om = 1.0f - p;
    const float fl = -yv * logf(p) * om * om;       // focal, gamma=2
    const float wl = 10.0f * expf(l) * (1.0f - labv) + labv;
    return runw * fl * wl;                          // /imb deferred
  };
  float s[8];
  s[0] = term(lg.x, y0, lb0); s[1] = term(lg.y, y1, lb1);
  s[2] = term(lg.z, y2, lb2); s[3] = term(lg.w, y3, 1.0f);
  s[4] = y0; s[5] = y1; s[6] = y2; s[7] = y3;

  #pragma unroll
  for (int k = 0; k < 8; ++k)
    #pragma unroll
    for (int off = 32; off; off >>= 1) s[k] += __shfl_xor(s[k], off);

  __shared__ float red[4][8];
  const int wv = t >> 6;
  if ((t & 63) == 0)
    #pragma unroll
    for (int k = 0; k < 8; ++k) red[wv][k] = s[k];
  __syncthreads();
  if (t < 8) {
    const float sum = red[0][t] + red[1][t] + red[2][t] + red[3][t];
    atomicAdd(&accum[t], sum);
  }
  __syncthreads();                                  // block's 8 adds drained
  if (t == 0) {
    __threadfence();
    const int ticket = __hip_atomic_fetch_add((int*)(accum + 8), 1,
                        __ATOMIC_ACQ_REL, __HIP_MEMORY_SCOPE_AGENT);
    if (ticket == 63) {                             // last block finalizes
      float L = 0.0f;
      #pragma unroll
      for (int c = 0; c < 4; ++c) {
        const float num = __hip_atomic_load(accum + c,
                            __ATOMIC_RELAXED, __HIP_MEMORY_SCOPE_AGENT);
        const float den = __hip_atomic_load(accum + 4 + c,
                            __ATOMIC_RELAXED, __HIP_MEMORY_SCOPE_AGENT);
        L += num / (den + 1e-7f);
      }
      loss[0] = L * 0.125f;                         // / bs, exact (pow2)
    }
  }
}

extern "C" void kernel_launch(void* const* d_in, const int* in_sizes, int n_in,
                              void* d_out, int out_size, void* d_ws, size_t ws_size,
                              hipStream_t stream)
{
  (void)in_sizes; (void)n_in; (void)out_size; (void)ws_size;
  const float* inp    = (const float*)d_in[0];
  const float* fcw    = (const float*)d_in[1];
  const float* fcb    = (const float*)d_in[2];
  const float* ps     = (const float*)d_in[3];
  const float* labels = (const float*)d_in[4];
  const float* rois   = (const float*)d_in[5];
  float* out = (float*)d_out;                       // 65536 logit + 1 loss

  char* ws = (char*)d_ws;
  float*  accum   = (float*) (ws);
  int*    meta    = (int*)   (ws + 64);
  float*  sList   = (float*) (ws + 1024);
  float*  areaL   = (float*) (ws + 197632);
  float4* roiL    = (float4*)(ws + 394240);
  float*  pbn     = (float*) (ws + 1180672);
  float*  pbd     = (float*) (ws + 1573888);
  int*    pbp     = (int*)   (ws + 1967104);

  k_sel <<<24,  256,  0, stream>>>(ps, labels, rois, accum, meta, sList, areaL, roiL);
  k_mid <<<512, 1024, 0, stream>>>(inp, fcw, fcb, rois, meta, roiL, areaL,
                                   out, pbn, pbd, pbp);
  k_back<<<64,  256,  0, stream>>>(pbn, pbd, pbp, sList, out, labels, accum,
                                   out + BSZ * PN * 4);
}